// Round 1
// baseline (718.047 us; speedup 1.0000x reference)
//
#include <hip/hip_runtime.h>

// Problem constants (fixed by reference)
#define HH   480
#define WW   640
#define HWP  (HH*WW)      // 307200 = 256 * 1200
#define NSEM 12
#define NINS 16
#define NCH  28           // sem channels then ins channels
#define NTHING 9

// ---------------------------------------------------------------------------
// 13-tap Gaussian (sigma=3, r=6), computed per-thread (cheap, avoids h2d copy)
// ---------------------------------------------------------------------------
__device__ __forceinline__ void gauss13(float k[13]) {
    float s = 0.f;
#pragma unroll
    for (int j = 0; j < 13; ++j) {
        float xx = (float)(j - 6);
        float v  = __expf(-(xx * xx) * (1.f / 18.f));   // exp(-0.5*(x/3)^2)
        k[j] = v; s += v;
    }
    float inv = 1.f / s;
#pragma unroll
    for (int j = 0; j < 13; ++j) k[j] *= inv;
}

template <int N>
__device__ __forceinline__ void softmaxN(const float* __restrict__ in, float* __restrict__ out) {
    float m = in[0];
#pragma unroll
    for (int i = 1; i < N; ++i) m = fmaxf(m, in[i]);
    float s = 0.f;
#pragma unroll
    for (int i = 0; i < N; ++i) { float e = __expf(in[i] - m); out[i] = e; s += e; }
    float inv = 1.f / s;
#pragma unroll
    for (int i = 0; i < N; ++i) out[i] *= inv;
}

// ---------------------------------------------------------------------------
// Precompute normalized bilateral weights: wn[d][p] = w_d(p) / sum_d w_d(p)
// Image-only; shared by sem/ins (ALPHA=3, BETA=0.15 for both) and all iters.
// ---------------------------------------------------------------------------
__global__ __launch_bounds__(256) void wn_kernel(const float* __restrict__ img,
                                                 float* __restrict__ wn) {
    int p = blockIdx.x * 256 + threadIdx.x;      // grid exactly covers HWP
    int y = p / WW, x = p - y * WW;
    float i0 = img[p], i1 = img[HWP + p], i2 = img[2 * HWP + p];
    float w[25];
    float den = 0.f;
    int d = 0;
#pragma unroll
    for (int dy = -2; dy <= 2; ++dy) {
        int yy = min(max(y + dy, 0), HH - 1);
#pragma unroll
        for (int dx = -2; dx <= 2; ++dx) {
            int xx = min(max(x + dx, 0), WW - 1);
            int pp = yy * WW + xx;
            float d0 = img[pp] - i0;
            float d1 = img[HWP + pp] - i1;
            float d2 = img[2 * HWP + pp] - i2;
            float cd = d0 * d0 + d1 * d1 + d2 * d2;
            float sd = (float)(dy * dy + dx * dx);
            // inv2a2 = 1/(2*3^2) = 1/18 ; inv2b2 = 1/(2*0.15^2) = 1/0.045
            float wv = __expf(-sd * (1.f / 18.f) - cd * (1.f / 0.045f));
            w[d++] = wv; den += wv;
        }
    }
    float inv = 1.f / den;
#pragma unroll
    for (int j = 0; j < 25; ++j) wn[j * HWP + p] = w[j] * inv;
}

// ---------------------------------------------------------------------------
// Initial softmax of the input logits -> q (28 planes: 12 sem then 16 ins)
// ---------------------------------------------------------------------------
__global__ __launch_bounds__(256) void softmax_init_kernel(const float* __restrict__ semL,
                                                           const float* __restrict__ insL,
                                                           float* __restrict__ q) {
    int p = blockIdx.x * 256 + threadIdx.x;
    float v[NINS], o[NINS];
#pragma unroll
    for (int i = 0; i < NSEM; ++i) v[i] = semL[i * HWP + p];
    softmaxN<NSEM>(v, o);
#pragma unroll
    for (int i = 0; i < NSEM; ++i) q[i * HWP + p] = o[i];
#pragma unroll
    for (int i = 0; i < NINS; ++i) v[i] = insL[i * HWP + p];
    softmaxN<NINS>(v, o);
#pragma unroll
    for (int i = 0; i < NINS; ++i) q[(NSEM + i) * HWP + p] = o[i];
}

// ---------------------------------------------------------------------------
// Separable blur, horizontal pass (zero padding, matches jax conv)
// ---------------------------------------------------------------------------
__global__ __launch_bounds__(256) void blur_h_kernel(const float* __restrict__ in,
                                                     float* __restrict__ out) {
    int idx = blockIdx.x * 256 + threadIdx.x;    // grid covers NCH*HWP exactly
    int c = idx / HWP;
    int p = idx - c * HWP;
    int y = p / WW, x = p - y * WW;
    float k[13]; gauss13(k);
    const float* row = in + c * HWP + y * WW;
    float acc = 0.f;
#pragma unroll
    for (int j = 0; j < 13; ++j) {
        int xx = x + j - 6;
        if (xx >= 0 && xx < WW) acc = fmaf(k[j], row[xx], acc);
    }
    out[idx] = acc;
}

// Vertical pass (zero padding)
__global__ __launch_bounds__(256) void blur_v_kernel(const float* __restrict__ in,
                                                     float* __restrict__ out) {
    int idx = blockIdx.x * 256 + threadIdx.x;
    int c = idx / HWP;
    int p = idx - c * HWP;
    int y = p / WW, x = p - y * WW;
    float k[13]; gauss13(k);
    const float* col = in + c * HWP + x;
    float acc = 0.f;
#pragma unroll
    for (int j = 0; j < 13; ++j) {
        int yy = y + j - 6;
        if (yy >= 0 && yy < HH) acc = fmaf(k[j], col[yy * WW], acc);
    }
    out[idx] = acc;
}

// ---------------------------------------------------------------------------
// Fused iteration tail:
//   bilateral gather (25 taps x 28 ch, precomputed normalized weights)
//   tmp_sem = semL + compat_sem( sw*sp + bw*bl )          (12x12)
//   tmp_ins = insL + sw_i*sp + bw_i*bl
//   tmp_sem += M_is^T softmax(tmp_ins)                    (16->12)
//   tmp_ins += M_si^T softmax(tmp_sem)                    (12->16)
//   qout = softmax(tmp_sem) ++ softmax(tmp_ins)
// ---------------------------------------------------------------------------
__global__ __launch_bounds__(256) void tail_kernel(const float* __restrict__ qin,
                                                   const float* __restrict__ sp,
                                                   const float* __restrict__ wn,
                                                   const float* __restrict__ semL,
                                                   const float* __restrict__ insL,
                                                   const float* __restrict__ sem_sw,
                                                   const float* __restrict__ sem_bw,
                                                   const float* __restrict__ sem_compat,
                                                   const float* __restrict__ ins_sw,
                                                   const float* __restrict__ ins_bw,
                                                   const int*   __restrict__ labels,
                                                   const float* __restrict__ cross_is,
                                                   const float* __restrict__ cross_si,
                                                   float* __restrict__ qout) {
    __shared__ float sC[NSEM * NSEM];    // sem_compat[i*12+o]
    __shared__ float sMis[NINS * NSEM];  // cross_ins_sem[labels[i]][o] at [i*12+o]
    __shared__ float sMsi[NINS * NSEM];  // cross_sem_ins[labels[o]][i] at [o*12+i]
    __shared__ float sws[NSEM], sbs[NSEM], swi[NINS], sbi[NINS];

    int t = threadIdx.x;
    if (t < NSEM * NSEM) sC[t] = sem_compat[t];
    if (t < NINS * NSEM) {
        int i = t / NSEM, o = t - i * NSEM;
        sMis[t] = cross_is[labels[i] * NSEM + o];
        int oo = t / NSEM, ii = t - oo * NSEM;
        sMsi[t] = cross_si[labels[oo] * NSEM + ii];
    }
    if (t < NSEM) { sws[t] = sem_sw[t]; sbs[t] = sem_bw[t]; }
    if (t < NINS) { int l = labels[t]; swi[t] = ins_sw[l]; sbi[t] = ins_bw[l]; }
    __syncthreads();

    int p = blockIdx.x * 256 + t;
    int y = p / WW, x = p - y * WW;

    // Bilateral gather for all 28 channels
    float bl[NCH];
#pragma unroll
    for (int c = 0; c < NCH; ++c) bl[c] = 0.f;
    int d = 0;
#pragma unroll
    for (int dy = -2; dy <= 2; ++dy) {
        int yy = min(max(y + dy, 0), HH - 1);
#pragma unroll
        for (int dx = -2; dx <= 2; ++dx) {
            int xx = min(max(x + dx, 0), WW - 1);
            int pp = yy * WW + xx;
            float wv = wn[d * HWP + p];
#pragma unroll
            for (int c = 0; c < NCH; ++c) bl[c] = fmaf(wv, qin[c * HWP + pp], bl[c]);
            ++d;
        }
    }

    // tmp_sem = semL + compat( sw*sp + bw*bl )
    float comb[NSEM];
#pragma unroll
    for (int i = 0; i < NSEM; ++i)
        comb[i] = sws[i] * sp[i * HWP + p] + sbs[i] * bl[i];
    float ts[NSEM];
#pragma unroll
    for (int o = 0; o < NSEM; ++o) {
        float a = semL[o * HWP + p];
#pragma unroll
        for (int i = 0; i < NSEM; ++i) a = fmaf(sC[i * NSEM + o], comb[i], a);
        ts[o] = a;
    }

    // tmp_ins
    float ti[NINS];
#pragma unroll
    for (int i = 0; i < NINS; ++i)
        ti[i] = insL[i * HWP + p] + swi[i] * sp[(NSEM + i) * HWP + p] + sbi[i] * bl[NSEM + i];

    // cross updates (use pre-update ts/ti on both sides, per reference)
    float sIns[NINS], sSem[NSEM];
    softmaxN<NINS>(ti, sIns);
    softmaxN<NSEM>(ts, sSem);

    float nts[NSEM];
#pragma unroll
    for (int o = 0; o < NSEM; ++o) {
        float a = ts[o];
#pragma unroll
        for (int i = 0; i < NINS; ++i) a = fmaf(sMis[i * NSEM + o], sIns[i], a);
        nts[o] = a;
    }
    float nti[NINS];
#pragma unroll
    for (int o = 0; o < NINS; ++o) {
        float a = ti[o];
#pragma unroll
        for (int i = 0; i < NSEM; ++i) a = fmaf(sMsi[o * NSEM + i], sSem[i], a);
        nti[o] = a;
    }

    // next-iteration q (or final output)
    float oq[NINS];
    softmaxN<NSEM>(nts, oq);
#pragma unroll
    for (int i = 0; i < NSEM; ++i) qout[i * HWP + p] = oq[i];
    softmaxN<NINS>(nti, oq);
#pragma unroll
    for (int i = 0; i < NINS; ++i) qout[(NSEM + i) * HWP + p] = oq[i];
}

// ---------------------------------------------------------------------------
extern "C" void kernel_launch(void* const* d_in, const int* in_sizes, int n_in,
                              void* d_out, int out_size, void* d_ws, size_t ws_size,
                              hipStream_t stream) {
    const float* image      = (const float*)d_in[0];
    const float* semL       = (const float*)d_in[1];
    const float* insL       = (const float*)d_in[2];
    const int*   labels     = (const int*)  d_in[3];
    const float* sem_sw     = (const float*)d_in[4];
    const float* sem_bw     = (const float*)d_in[5];
    const float* sem_compat = (const float*)d_in[6];
    const float* ins_sw     = (const float*)d_in[7];
    const float* ins_bw     = (const float*)d_in[8];
    const float* cross_is   = (const float*)d_in[9];
    const float* cross_si   = (const float*)d_in[10];
    float* out = (float*)d_out;

    // Workspace layout (fp32): wn[25*HW] | A[28*HW] | B[28*HW] | S[28*HW]
    // total 109*HW floats = ~134 MB
    float* ws = (float*)d_ws;
    float* wn = ws;
    float* A  = wn + (size_t)25 * HWP;
    float* B  = A  + (size_t)NCH * HWP;
    float* S  = B  + (size_t)NCH * HWP;

    const int PIX_BLOCKS = HWP / 256;        // 1200
    const int CH_BLOCKS  = NCH * HWP / 256;  // 33600

    wn_kernel<<<PIX_BLOCKS, 256, 0, stream>>>(image, wn);
    softmax_init_kernel<<<PIX_BLOCKS, 256, 0, stream>>>(semL, insL, A);

    // iter 0: q=A, temp=B, sp=S, out->B (B is dead after blur_v)
    // iter 1: q=B, temp=A, sp=S, out->A
    // iter 2: q=A, temp=B, sp=S, out->d_out
    float* qin[3]  = { A, B, A };
    float* tmp[3]  = { B, A, B };
    float* qout[3] = { B, A, out };

    for (int it = 0; it < 3; ++it) {
        blur_h_kernel<<<CH_BLOCKS, 256, 0, stream>>>(qin[it], tmp[it]);
        blur_v_kernel<<<CH_BLOCKS, 256, 0, stream>>>(tmp[it], S);
        tail_kernel<<<PIX_BLOCKS, 256, 0, stream>>>(qin[it], S, wn, semL, insL,
                                                    sem_sw, sem_bw, sem_compat,
                                                    ins_sw, ins_bw, labels,
                                                    cross_is, cross_si, qout[it]);
    }
}

// Round 2
// 459.644 us; speedup vs baseline: 1.5622x; 1.5622x over previous
//
#include <hip/hip_runtime.h>

// Problem constants (fixed by reference)
#define HH   480
#define WW   640
#define HWP  (HH*WW)      // 307200 = 256 * 1200
#define NSEM 12
#define NINS 16
#define NCH  28           // sem channels then ins channels

// ---------------------------------------------------------------------------
// 13-tap Gaussian (sigma=3, r=6), computed per-thread
// ---------------------------------------------------------------------------
__device__ __forceinline__ void gauss13(float k[13]) {
    float s = 0.f;
#pragma unroll
    for (int j = 0; j < 13; ++j) {
        float xx = (float)(j - 6);
        float v  = __expf(-(xx * xx) * (1.f / 18.f));
        k[j] = v; s += v;
    }
    float inv = 1.f / s;
#pragma unroll
    for (int j = 0; j < 13; ++j) k[j] *= inv;
}

template <int N>
__device__ __forceinline__ void softmaxN(const float* __restrict__ in, float* __restrict__ out) {
    float m = in[0];
#pragma unroll
    for (int i = 1; i < N; ++i) m = fmaxf(m, in[i]);
    float s = 0.f;
#pragma unroll
    for (int i = 0; i < N; ++i) { float e = __expf(in[i] - m); out[i] = e; s += e; }
    float inv = 1.f / s;
#pragma unroll
    for (int i = 0; i < N; ++i) out[i] *= inv;
}

// ---------------------------------------------------------------------------
// Precompute normalized bilateral weights (image-only, shared sem/ins & iters)
// ---------------------------------------------------------------------------
__global__ __launch_bounds__(256) void wn_kernel(const float* __restrict__ img,
                                                 float* __restrict__ wn) {
    int p = blockIdx.x * 256 + threadIdx.x;
    int y = p / WW, x = p - y * WW;
    float i0 = img[p], i1 = img[HWP + p], i2 = img[2 * HWP + p];
    float w[25];
    float den = 0.f;
    int d = 0;
#pragma unroll
    for (int dy = -2; dy <= 2; ++dy) {
        int yy = min(max(y + dy, 0), HH - 1);
#pragma unroll
        for (int dx = -2; dx <= 2; ++dx) {
            int xx = min(max(x + dx, 0), WW - 1);
            int pp = yy * WW + xx;
            float d0 = img[pp] - i0;
            float d1 = img[HWP + pp] - i1;
            float d2 = img[2 * HWP + pp] - i2;
            float cd = d0 * d0 + d1 * d1 + d2 * d2;
            float sd = (float)(dy * dy + dx * dx);
            float wv = __expf(-sd * (1.f / 18.f) - cd * (1.f / 0.045f));
            w[d++] = wv; den += wv;
        }
    }
    float inv = 1.f / den;
#pragma unroll
    for (int j = 0; j < 25; ++j) wn[j * HWP + p] = w[j] * inv;
}

// ---------------------------------------------------------------------------
// Initial softmax of the input logits -> q (28 planes)
// ---------------------------------------------------------------------------
__global__ __launch_bounds__(256) void softmax_init_kernel(const float* __restrict__ semL,
                                                           const float* __restrict__ insL,
                                                           float* __restrict__ q) {
    int p = blockIdx.x * 256 + threadIdx.x;
    float v[NINS], o[NINS];
#pragma unroll
    for (int i = 0; i < NSEM; ++i) v[i] = semL[i * HWP + p];
    softmaxN<NSEM>(v, o);
#pragma unroll
    for (int i = 0; i < NSEM; ++i) q[i * HWP + p] = o[i];
#pragma unroll
    for (int i = 0; i < NINS; ++i) v[i] = insL[i * HWP + p];
    softmaxN<NINS>(v, o);
#pragma unroll
    for (int i = 0; i < NINS; ++i) q[(NSEM + i) * HWP + p] = o[i];
}

// ---------------------------------------------------------------------------
// Fused separable 13x13 blur (zero pad), LDS-tiled. Tile 64x32 per block.
// raw tile (76x44) -> hblur (64x44) -> vblur (64x32)
// ---------------------------------------------------------------------------
#define BTW 64
#define BTH 32
#define BR  6
__global__ __launch_bounds__(256) void blur_fused_kernel(const float* __restrict__ in,
                                                         float* __restrict__ out) {
    __shared__ float raw[(BTH + 2 * BR) * (BTW + 2 * BR)];  // 44*76
    __shared__ float hb[(BTH + 2 * BR) * BTW];              // 44*64
    const int t  = threadIdx.x;
    const int x0 = blockIdx.x * BTW;
    const int y0 = blockIdx.y * BTH;
    const int c  = blockIdx.z;
    const float* __restrict__ plane = in + (size_t)c * HWP;

    float k[13]; gauss13(k);

    // Load raw tile (zero pad outside image)
    const int RAWW = BTW + 2 * BR;            // 76
    const int RAWN = RAWW * (BTH + 2 * BR);   // 3344
    for (int idx = t; idx < RAWN; idx += 256) {
        int ly = idx / RAWW, lx = idx - ly * RAWW;
        int gy = y0 - BR + ly, gx = x0 - BR + lx;
        float v = 0.f;
        if (gy >= 0 && gy < HH && gx >= 0 && gx < WW) v = plane[gy * WW + gx];
        raw[idx] = v;
    }
    __syncthreads();

    // Horizontal pass: 64 x 44
    const int HBN = BTW * (BTH + 2 * BR);     // 2816
    for (int idx = t; idx < HBN; idx += 256) {
        int ly = idx / BTW, lx = idx - ly * BTW;
        const float* r = raw + ly * RAWW + lx;
        float acc = 0.f;
#pragma unroll
        for (int j = 0; j < 13; ++j) acc = fmaf(k[j], r[j], acc);
        hb[idx] = acc;
    }
    __syncthreads();

    // Vertical pass: 64 x 32 -> global
    for (int idx = t; idx < BTW * BTH; idx += 256) {
        int ly = idx / BTW, lx = idx - ly * BTW;
        const float* hcol = hb + ly * BTW + lx;
        float acc = 0.f;
#pragma unroll
        for (int j = 0; j < 13; ++j) acc = fmaf(k[j], hcol[j * BTW], acc);
        out[(size_t)c * HWP + (y0 + ly) * WW + (x0 + lx)] = acc;
    }
}

// ---------------------------------------------------------------------------
// Fused iteration tail, LDS-tiled bilateral gather.
// Block = 256 threads covering a 64x4 pixel tile; channels staged in LDS in
// groups of 7 (8 rows x 68 cols windows, edge-clamped).
// ---------------------------------------------------------------------------
#define TTW 64
#define TTH 4
#define GC  7                 // channels per LDS group
#define TWIN_W (TTW + 4)      // 68
#define TWIN_H (TTH + 4)      // 8
#define TWIN_N (TWIN_W * TWIN_H)  // 544

__global__ __launch_bounds__(256) void tail_kernel(const float* __restrict__ qin,
                                                   const float* __restrict__ sp,
                                                   const float* __restrict__ wn,
                                                   const float* __restrict__ semL,
                                                   const float* __restrict__ insL,
                                                   const float* __restrict__ sem_sw,
                                                   const float* __restrict__ sem_bw,
                                                   const float* __restrict__ sem_compat,
                                                   const float* __restrict__ ins_sw,
                                                   const float* __restrict__ ins_bw,
                                                   const int*   __restrict__ labels,
                                                   const float* __restrict__ cross_is,
                                                   const float* __restrict__ cross_si,
                                                   float* __restrict__ qout) {
    __shared__ float lq[GC * TWIN_N];          // 7*544 floats = 15232 B
    __shared__ float sC[NSEM * NSEM];
    __shared__ float sMis[NINS * NSEM];
    __shared__ float sMsi[NINS * NSEM];
    __shared__ float sws[NSEM], sbs[NSEM], swi[NINS], sbi[NINS];

    const int t  = threadIdx.x;
    const int tx = t & 63;
    const int ty = t >> 6;
    const int x0 = blockIdx.x * TTW;
    const int y0 = blockIdx.y * TTH;
    const int x  = x0 + tx;
    const int y  = y0 + ty;
    const int p  = y * WW + x;

    if (t < NSEM * NSEM) sC[t] = sem_compat[t];
    if (t < NINS * NSEM) {
        int i = t / NSEM, o = t - i * NSEM;
        sMis[t] = cross_is[labels[i] * NSEM + o];
        sMsi[t] = cross_si[labels[i] * NSEM + o];  // [o_ins*12 + i_sem] layout
    }
    if (t < NSEM) { sws[t] = sem_sw[t]; sbs[t] = sem_bw[t]; }
    if (t < NINS) { int l = labels[t]; swi[t] = ins_sw[l]; sbi[t] = ins_bw[l]; }

    // per-pixel normalized bilateral weights into registers
    float wnr[25];
#pragma unroll
    for (int d = 0; d < 25; ++d) wnr[d] = wn[d * HWP + p];

    float bl[NCH];
#pragma unroll
    for (int c = 0; c < NCH; ++c) bl[c] = 0.f;

    // channel groups of 7
    for (int g = 0; g < NCH / GC; ++g) {
        const int c0 = g * GC;
        __syncthreads();   // protect previous group's reads
        for (int idx = t; idx < GC * TWIN_N; idx += 256) {
            int cc  = idx / TWIN_N;
            int rem = idx - cc * TWIN_N;
            int ly  = rem / TWIN_W, lx = rem - ly * TWIN_W;
            int gy  = min(max(y0 - 2 + ly, 0), HH - 1);
            int gx  = min(max(x0 - 2 + lx, 0), WW - 1);
            lq[idx] = qin[(size_t)(c0 + cc) * HWP + gy * WW + gx];
        }
        __syncthreads();
#pragma unroll
        for (int cc = 0; cc < GC; ++cc) {
            const float* w0 = lq + cc * TWIN_N + ty * TWIN_W + tx;  // (dy,dx)=(-2,-2)
            float a = 0.f;
            int d = 0;
#pragma unroll
            for (int dy = 0; dy < 5; ++dy)
#pragma unroll
                for (int dx = 0; dx < 5; ++dx)
                    a = fmaf(wnr[d++], w0[dy * TWIN_W + dx], a);
            bl[c0 + cc] = a;
        }
    }

    // tmp_sem = semL + compat( sw*sp + bw*bl )
    float comb[NSEM];
#pragma unroll
    for (int i = 0; i < NSEM; ++i)
        comb[i] = sws[i] * sp[i * HWP + p] + sbs[i] * bl[i];
    float ts[NSEM];
#pragma unroll
    for (int o = 0; o < NSEM; ++o) {
        float a = semL[o * HWP + p];
#pragma unroll
        for (int i = 0; i < NSEM; ++i) a = fmaf(sC[i * NSEM + o], comb[i], a);
        ts[o] = a;
    }

    // tmp_ins
    float ti[NINS];
#pragma unroll
    for (int i = 0; i < NINS; ++i)
        ti[i] = insL[i * HWP + p] + swi[i] * sp[(NSEM + i) * HWP + p] + sbi[i] * bl[NSEM + i];

    // cross updates (pre-update ts/ti on both sides)
    float sIns[NINS], sSem[NSEM];
    softmaxN<NINS>(ti, sIns);
    softmaxN<NSEM>(ts, sSem);

    float nts[NSEM];
#pragma unroll
    for (int o = 0; o < NSEM; ++o) {
        float a = ts[o];
#pragma unroll
        for (int i = 0; i < NINS; ++i) a = fmaf(sMis[i * NSEM + o], sIns[i], a);
        nts[o] = a;
    }
    float nti[NINS];
#pragma unroll
    for (int o = 0; o < NINS; ++o) {
        float a = ti[o];
#pragma unroll
        for (int i = 0; i < NSEM; ++i) a = fmaf(sMsi[o * NSEM + i], sSem[i], a);
        nti[o] = a;
    }

    float oq[NINS];
    softmaxN<NSEM>(nts, oq);
#pragma unroll
    for (int i = 0; i < NSEM; ++i) qout[i * HWP + p] = oq[i];
    softmaxN<NINS>(nti, oq);
#pragma unroll
    for (int i = 0; i < NINS; ++i) qout[(NSEM + i) * HWP + p] = oq[i];
}

// ---------------------------------------------------------------------------
extern "C" void kernel_launch(void* const* d_in, const int* in_sizes, int n_in,
                              void* d_out, int out_size, void* d_ws, size_t ws_size,
                              hipStream_t stream) {
    const float* image      = (const float*)d_in[0];
    const float* semL       = (const float*)d_in[1];
    const float* insL       = (const float*)d_in[2];
    const int*   labels     = (const int*)  d_in[3];
    const float* sem_sw     = (const float*)d_in[4];
    const float* sem_bw     = (const float*)d_in[5];
    const float* sem_compat = (const float*)d_in[6];
    const float* ins_sw     = (const float*)d_in[7];
    const float* ins_bw     = (const float*)d_in[8];
    const float* cross_is   = (const float*)d_in[9];
    const float* cross_si   = (const float*)d_in[10];
    float* out = (float*)d_out;

    // Workspace layout (fp32): wn[25*HW] | A[28*HW] | B[28*HW] | S[28*HW]
    float* ws = (float*)d_ws;
    float* wn = ws;
    float* A  = wn + (size_t)25 * HWP;
    float* B  = A  + (size_t)NCH * HWP;
    float* S  = B  + (size_t)NCH * HWP;

    const int PIX_BLOCKS = HWP / 256;  // 1200

    wn_kernel<<<PIX_BLOCKS, 256, 0, stream>>>(image, wn);
    softmax_init_kernel<<<PIX_BLOCKS, 256, 0, stream>>>(semL, insL, A);

    dim3 bgrid(WW / BTW, HH / BTH, NCH);    // 10 x 15 x 28
    dim3 tgrid(WW / TTW, HH / TTH);         // 10 x 120

    float* qin[3]  = { A, B, A };
    float* qout[3] = { B, A, out };

    for (int it = 0; it < 3; ++it) {
        blur_fused_kernel<<<bgrid, 256, 0, stream>>>(qin[it], S);
        tail_kernel<<<tgrid, 256, 0, stream>>>(qin[it], S, wn, semL, insL,
                                               sem_sw, sem_bw, sem_compat,
                                               ins_sw, ins_bw, labels,
                                               cross_is, cross_si, qout[it]);
    }
}

// Round 3
// 401.038 us; speedup vs baseline: 1.7905x; 1.1461x over previous
//
#include <hip/hip_runtime.h>

// Problem constants (fixed by reference)
#define HH   480
#define WW   640
#define HWP  (HH*WW)      // 307200 = 256 * 1200
#define NSEM 12
#define NINS 16
#define NCH  28           // sem channels then ins channels

// ---------------------------------------------------------------------------
// 13-tap Gaussian (sigma=3, r=6), computed per-thread
// ---------------------------------------------------------------------------
__device__ __forceinline__ void gauss13(float k[13]) {
    float s = 0.f;
#pragma unroll
    for (int j = 0; j < 13; ++j) {
        float xx = (float)(j - 6);
        float v  = __expf(-(xx * xx) * (1.f / 18.f));
        k[j] = v; s += v;
    }
    float inv = 1.f / s;
#pragma unroll
    for (int j = 0; j < 13; ++j) k[j] *= inv;
}

template <int N>
__device__ __forceinline__ void softmaxN(const float* __restrict__ in, float* __restrict__ out) {
    float m = in[0];
#pragma unroll
    for (int i = 1; i < N; ++i) m = fmaxf(m, in[i]);
    float s = 0.f;
#pragma unroll
    for (int i = 0; i < N; ++i) { float e = __expf(in[i] - m); out[i] = e; s += e; }
    float inv = 1.f / s;
#pragma unroll
    for (int i = 0; i < N; ++i) out[i] *= inv;
}

// ---------------------------------------------------------------------------
// Initial softmax of the input logits -> q (28 planes)
// ---------------------------------------------------------------------------
__global__ __launch_bounds__(256) void softmax_init_kernel(const float* __restrict__ semL,
                                                           const float* __restrict__ insL,
                                                           float* __restrict__ q) {
    int p = blockIdx.x * 256 + threadIdx.x;
    float v[NINS], o[NINS];
#pragma unroll
    for (int i = 0; i < NSEM; ++i) v[i] = semL[i * HWP + p];
    softmaxN<NSEM>(v, o);
#pragma unroll
    for (int i = 0; i < NSEM; ++i) q[i * HWP + p] = o[i];
#pragma unroll
    for (int i = 0; i < NINS; ++i) v[i] = insL[i * HWP + p];
    softmaxN<NINS>(v, o);
#pragma unroll
    for (int i = 0; i < NINS; ++i) q[(NSEM + i) * HWP + p] = o[i];
}

// ---------------------------------------------------------------------------
// Fused separable 13x13 blur (zero pad), LDS-tiled. Tile 64x32 per block.
// ---------------------------------------------------------------------------
#define BTW 64
#define BTH 32
#define BR  6
__global__ __launch_bounds__(256) void blur_fused_kernel(const float* __restrict__ in,
                                                         float* __restrict__ out) {
    __shared__ float raw[(BTH + 2 * BR) * (BTW + 2 * BR)];  // 44*76
    __shared__ float hb[(BTH + 2 * BR) * BTW];              // 44*64
    const int t  = threadIdx.x;
    const int x0 = blockIdx.x * BTW;
    const int y0 = blockIdx.y * BTH;
    const int c  = blockIdx.z;
    const float* __restrict__ plane = in + (size_t)c * HWP;

    float k[13]; gauss13(k);

    const int RAWW = BTW + 2 * BR;            // 76
    const int RAWN = RAWW * (BTH + 2 * BR);   // 3344
    for (int idx = t; idx < RAWN; idx += 256) {
        int ly = idx / RAWW, lx = idx - ly * RAWW;
        int gy = y0 - BR + ly, gx = x0 - BR + lx;
        float v = 0.f;
        if (gy >= 0 && gy < HH && gx >= 0 && gx < WW) v = plane[gy * WW + gx];
        raw[idx] = v;
    }
    __syncthreads();

    const int HBN = BTW * (BTH + 2 * BR);     // 2816
    for (int idx = t; idx < HBN; idx += 256) {
        int ly = idx / BTW, lx = idx - ly * BTW;
        const float* r = raw + ly * RAWW + lx;
        float acc = 0.f;
#pragma unroll
        for (int j = 0; j < 13; ++j) acc = fmaf(k[j], r[j], acc);
        hb[idx] = acc;
    }
    __syncthreads();

    for (int idx = t; idx < BTW * BTH; idx += 256) {
        int ly = idx / BTW, lx = idx - ly * BTW;
        const float* hcol = hb + ly * BTW + lx;
        float acc = 0.f;
#pragma unroll
        for (int j = 0; j < 13; ++j) acc = fmaf(k[j], hcol[j * BTW], acc);
        out[(size_t)c * HWP + (y0 + ly) * WW + (x0 + lx)] = acc;
    }
}

// ---------------------------------------------------------------------------
// Fused iteration tail. 64x4 pixel tile / 256 threads.
// - bilateral weights recomputed in-kernel from LDS-staged image window
// - q staged in channel groups of 7, DOUBLE-BUFFERED (overlap load & compute)
// ---------------------------------------------------------------------------
#define TTW 64
#define TTH 4
#define GC  7                 // channels per LDS group
#define NG  (NCH / GC)        // 4 groups
#define TWIN_W (TTW + 4)      // 68
#define TWIN_H (TTH + 4)      // 8
#define TWIN_N (TWIN_W * TWIN_H)  // 544
#define GN  (GC * TWIN_N)     // 3808
#define NSLOT ((GN + 255) / 256)  // 15 staging slots per thread

__global__ __launch_bounds__(256) void tail_kernel(const float* __restrict__ qin,
                                                   const float* __restrict__ sp,
                                                   const float* __restrict__ img,
                                                   const float* __restrict__ semL,
                                                   const float* __restrict__ insL,
                                                   const float* __restrict__ sem_sw,
                                                   const float* __restrict__ sem_bw,
                                                   const float* __restrict__ sem_compat,
                                                   const float* __restrict__ ins_sw,
                                                   const float* __restrict__ ins_bw,
                                                   const int*   __restrict__ labels,
                                                   const float* __restrict__ cross_is,
                                                   const float* __restrict__ cross_si,
                                                   float* __restrict__ qout) {
    __shared__ float lq[2][GN];            // 2 x 15232 B
    __shared__ float limg[3 * TWIN_N];     // 6528 B
    __shared__ float sC[NSEM * NSEM];
    __shared__ float sMis[NINS * NSEM];
    __shared__ float sMsi[NINS * NSEM];
    __shared__ float sws[NSEM], sbs[NSEM], swi[NINS], sbi[NINS];

    const int t  = threadIdx.x;
    const int tx = t & 63;
    const int ty = t >> 6;
    const int x0 = blockIdx.x * TTW;
    const int y0 = blockIdx.y * TTH;
    const int x  = x0 + tx;
    const int y  = y0 + ty;
    const int p  = y * WW + x;

    if (t < NSEM * NSEM) sC[t] = sem_compat[t];
    if (t < NINS * NSEM) {
        int i = t / NSEM, o = t - i * NSEM;
        sMis[t] = cross_is[labels[i] * NSEM + o];
        sMsi[t] = cross_si[labels[i] * NSEM + o];  // [o_ins*12 + i_sem]
    }
    if (t < NSEM) { sws[t] = sem_sw[t]; sbs[t] = sem_bw[t]; }
    if (t < NINS) { int l = labels[t]; swi[t] = ins_sw[l]; sbi[t] = ins_bw[l]; }

    // ---- precompute staging offsets (same clamped gy/gx for every group) ----
    int goff[NSLOT];
#pragma unroll
    for (int j = 0; j < NSLOT; ++j) {
        int idx = t + j * 256;
        if (idx < GN) {
            int cc  = idx / TWIN_N;
            int rem = idx - cc * TWIN_N;
            int ly  = rem / TWIN_W, lx = rem - ly * TWIN_W;
            int gy  = min(max(y0 - 2 + ly, 0), HH - 1);
            int gx  = min(max(x0 - 2 + lx, 0), WW - 1);
            goff[j] = cc * HWP + gy * WW + gx;
        } else goff[j] = 0;
    }

    // ---- stage image window (3 channels, edge-clamped) ----
    for (int idx = t; idx < 3 * TWIN_N; idx += 256) {
        int cc  = idx / TWIN_N;
        int rem = idx - cc * TWIN_N;
        int ly  = rem / TWIN_W, lx = rem - ly * TWIN_W;
        int gy  = min(max(y0 - 2 + ly, 0), HH - 1);
        int gx  = min(max(x0 - 2 + lx, 0), WW - 1);
        limg[idx] = img[(size_t)cc * HWP + gy * WW + gx];
    }

    // ---- stage q group 0 into buffer 0 ----
#pragma unroll
    for (int j = 0; j < NSLOT; ++j) {
        int idx = t + j * 256;
        if (idx < GN) lq[0][idx] = qin[goff[j]];
    }
    __syncthreads();

    // ---- per-pixel bilateral weights from the staged image window ----
    const int wc = (ty + 2) * TWIN_W + (tx + 2);  // this pixel in window coords
    float i0 = limg[wc], i1 = limg[TWIN_N + wc], i2 = limg[2 * TWIN_N + wc];
    float wnr[25];
    float den = 0.f;
    {
        int d = 0;
#pragma unroll
        for (int dy = 0; dy < 5; ++dy) {
#pragma unroll
            for (int dx = 0; dx < 5; ++dx) {
                int nb = (ty + dy) * TWIN_W + (tx + dx);
                float d0 = limg[nb] - i0;
                float d1 = limg[TWIN_N + nb] - i1;
                float d2 = limg[2 * TWIN_N + nb] - i2;
                float cd = d0 * d0 + d1 * d1 + d2 * d2;
                float sd = (float)((dy - 2) * (dy - 2) + (dx - 2) * (dx - 2));
                float wv = __expf(-sd * (1.f / 18.f) - cd * (1.f / 0.045f));
                wnr[d++] = wv; den += wv;
            }
        }
        float inv = 1.f / den;
#pragma unroll
        for (int j = 0; j < 25; ++j) wnr[j] *= inv;
    }

    // ---- bilateral gather, double-buffered channel groups ----
    float bl[NCH];
#pragma unroll
    for (int c = 0; c < NCH; ++c) bl[c] = 0.f;

    for (int g = 0; g < NG; ++g) {
        // prefetch next group into the other buffer (overlaps with compute)
        if (g + 1 < NG) {
            const float* pl = qin + (size_t)(g + 1) * GC * HWP;
            float* dst = lq[(g + 1) & 1];
#pragma unroll
            for (int j = 0; j < NSLOT; ++j) {
                int idx = t + j * 256;
                if (idx < GN) dst[idx] = pl[goff[j]];
            }
        }
        const float* base = lq[g & 1];
        const int c0 = g * GC;
#pragma unroll
        for (int cc = 0; cc < GC; ++cc) {
            const float* w0 = base + cc * TWIN_N + ty * TWIN_W + tx;
            float a = 0.f;
            int d = 0;
#pragma unroll
            for (int dy = 0; dy < 5; ++dy)
#pragma unroll
                for (int dx = 0; dx < 5; ++dx)
                    a = fmaf(wnr[d++], w0[dy * TWIN_W + dx], a);
            bl[c0 + cc] = a;
        }
        __syncthreads();  // staged writes visible; reads of base done
    }

    // ---- pointwise tail ----
    float comb[NSEM];
#pragma unroll
    for (int i = 0; i < NSEM; ++i)
        comb[i] = sws[i] * sp[i * HWP + p] + sbs[i] * bl[i];
    float ts[NSEM];
#pragma unroll
    for (int o = 0; o < NSEM; ++o) {
        float a = semL[o * HWP + p];
#pragma unroll
        for (int i = 0; i < NSEM; ++i) a = fmaf(sC[i * NSEM + o], comb[i], a);
        ts[o] = a;
    }

    float ti[NINS];
#pragma unroll
    for (int i = 0; i < NINS; ++i)
        ti[i] = insL[i * HWP + p] + swi[i] * sp[(NSEM + i) * HWP + p] + sbi[i] * bl[NSEM + i];

    float sIns[NINS], sSem[NSEM];
    softmaxN<NINS>(ti, sIns);
    softmaxN<NSEM>(ts, sSem);

    float nts[NSEM];
#pragma unroll
    for (int o = 0; o < NSEM; ++o) {
        float a = ts[o];
#pragma unroll
        for (int i = 0; i < NINS; ++i) a = fmaf(sMis[i * NSEM + o], sIns[i], a);
        nts[o] = a;
    }
    float nti[NINS];
#pragma unroll
    for (int o = 0; o < NINS; ++o) {
        float a = ti[o];
#pragma unroll
        for (int i = 0; i < NSEM; ++i) a = fmaf(sMsi[o * NSEM + i], sSem[i], a);
        nti[o] = a;
    }

    float oq[NINS];
    softmaxN<NSEM>(nts, oq);
#pragma unroll
    for (int i = 0; i < NSEM; ++i) qout[i * HWP + p] = oq[i];
    softmaxN<NINS>(nti, oq);
#pragma unroll
    for (int i = 0; i < NINS; ++i) qout[(NSEM + i) * HWP + p] = oq[i];
}

// ---------------------------------------------------------------------------
extern "C" void kernel_launch(void* const* d_in, const int* in_sizes, int n_in,
                              void* d_out, int out_size, void* d_ws, size_t ws_size,
                              hipStream_t stream) {
    const float* image      = (const float*)d_in[0];
    const float* semL       = (const float*)d_in[1];
    const float* insL       = (const float*)d_in[2];
    const int*   labels     = (const int*)  d_in[3];
    const float* sem_sw     = (const float*)d_in[4];
    const float* sem_bw     = (const float*)d_in[5];
    const float* sem_compat = (const float*)d_in[6];
    const float* ins_sw     = (const float*)d_in[7];
    const float* ins_bw     = (const float*)d_in[8];
    const float* cross_is   = (const float*)d_in[9];
    const float* cross_si   = (const float*)d_in[10];
    float* out = (float*)d_out;

    // Workspace: A[28*HW] | B[28*HW] | S[28*HW]  (fp32)
    float* ws = (float*)d_ws;
    float* A  = ws;
    float* B  = A + (size_t)NCH * HWP;
    float* S  = B + (size_t)NCH * HWP;

    const int PIX_BLOCKS = HWP / 256;  // 1200

    softmax_init_kernel<<<PIX_BLOCKS, 256, 0, stream>>>(semL, insL, A);

    dim3 bgrid(WW / BTW, HH / BTH, NCH);    // 10 x 15 x 28
    dim3 tgrid(WW / TTW, HH / TTH);         // 10 x 120

    float* qin[3]  = { A, B, A };
    float* qout[3] = { B, A, out };

    for (int it = 0; it < 3; ++it) {
        blur_fused_kernel<<<bgrid, 256, 0, stream>>>(qin[it], S);
        tail_kernel<<<tgrid, 256, 0, stream>>>(qin[it], S, image, semL, insL,
                                               sem_sw, sem_bw, sem_compat,
                                               ins_sw, ins_bw, labels,
                                               cross_is, cross_si, qout[it]);
    }
}